// Round 1
// baseline (119.311 us; speedup 1.0000x reference)
//
#include <hip/hip_runtime.h>
#include <hip/hip_bf16.h>

using u16 = unsigned short;
using u32 = unsigned int;

typedef __attribute__((ext_vector_type(8))) short s16x8;
typedef __attribute__((ext_vector_type(4))) float f32x4;
typedef __attribute__((ext_vector_type(4))) u32   u32x4;

#define NQ   74      // K chunks of 32 (2368 padded features)
#define NRUN 296     // 8-runs: 8 linear + 288 quad
#define BM   128     // pixels per block

__device__ __forceinline__ u16 f2bf_rne(float f) {
    u32 u = __builtin_bit_cast(u32, f);
    u32 r = u + 0x7fffu + ((u >> 16) & 1u);
    return (u16)(r >> 16);
}
__device__ __forceinline__ float bf2f(u16 u) {
    u32 v = ((u32)u) << 16;
    return __builtin_bit_cast(float, v);
}

// run r -> (i, j0). r<8: linear terms (i=64 means "ones"); else quad row i,
// runs start at j0=(i>>3)*8 (leading j<i entries carry zero weights).
__device__ __forceinline__ void run_decode(int r, int& i, int& j0) {
    if (r < 8) { i = 64; j0 = r << 3; return; }
    int rr = r - 8;
    int ii = 0;
    while (true) { int cnt = 8 - (ii >> 3); if (rr < cnt) break; rr -= cnt; ++ii; }
    i = ii;
    j0 = ((ii >> 3) << 3) + (rr << 3);
}

// Repack fc_w [256][2144] f32 -> bf16 MFMA A-fragment order:
// wpk[(q*16+t)*64 + l] holds 8 bf16: n = t*16+(l&15), k-run = q*4+(l>>4), e=0..7
__global__ __launch_bounds__(256) void pack_w(const float* __restrict__ fcw,
                                              s16x8* __restrict__ wpk) {
    int tid = blockIdx.x * 256 + threadIdx.x;
    if (tid >= NQ * 1024) return;
    int l = tid & 63;
    int t = (tid >> 6) & 15;
    int q = tid >> 10;
    int g = l >> 4;
    int n = t * 16 + (l & 15);
    int i, j0; run_decode(q * 4 + g, i, j0);
    const float* row = fcw + n * 2144;
    short w8[8];
    #pragma unroll
    for (int e = 0; e < 8; ++e) {
        int j = j0 + e;
        float w;
        if (i == 64)    w = row[j];                                          // linear
        else if (j < i) w = 0.f;                                             // pad
        else            w = row[64 + i * 64 - ((i * (i - 1)) >> 1) + (j - i)]; // triu
        w8[e] = (short)f2bf_rne(w);
    }
    s16x8 v = { w8[0], w8[1], w8[2], w8[3], w8[4], w8[5], w8[6], w8[7] };
    wpk[tid] = v;
}

#define LOADW(Q, WF) do {                                                    \
    const s16x8* bp_ = wpk + ((((Q) * 16) + wn4) << 6) + l;                  \
    WF[0] = bp_[0]; WF[1] = bp_[64]; WF[2] = bp_[128]; WF[3] = bp_[192];     \
} while (0)

#define GEN(Q, BUF) do {                                                     \
    u16 ij_ = runtab[(Q) * 4 + g2];                                          \
    int i_ = ij_ >> 8, j0_ = ij_ & 255;                                      \
    float fi_ = bf2f(x_lds[xmb + ((i_ & 63) ^ sw)]);                         \
    if (i_ >= 64) fi_ = 1.0f;                                                \
    s16x8 vj_ = *(const s16x8*)(x_lds + xmb + (j0_ ^ sw));                   \
    u32 pk_[4];                                                              \
    _Pragma("unroll")                                                        \
    for (int d_ = 0; d_ < 4; ++d_) {                                         \
        float p0_ = fi_ * bf2f((u16)vj_[2 * d_]);                            \
        float p1_ = fi_ * bf2f((u16)vj_[2 * d_ + 1]);                        \
        pk_[d_] = __builtin_amdgcn_perm(__builtin_bit_cast(u32, p1_),        \
                                        __builtin_bit_cast(u32, p0_),        \
                                        0x07060302u);                        \
    }                                                                        \
    u32x4 pv_ = { pk_[0], pk_[1], pk_[2], pk_[3] };                          \
    ybuf[BUF][ygidx] = __builtin_bit_cast(s16x8, pv_);                       \
} while (0)

#define CONSUME(BUF, WF) do {                                                \
    s16x8 yf_[4];                                                            \
    _Pragma("unroll")                                                        \
    for (int mi_ = 0; mi_ < 4; ++mi_) yf_[mi_] = ybuf[BUF][ycbase + mi_ * 16]; \
    _Pragma("unroll")                                                        \
    for (int mi_ = 0; mi_ < 4; ++mi_)                                        \
        _Pragma("unroll")                                                    \
        for (int ni_ = 0; ni_ < 4; ++ni_)                                    \
            acc[mi_][ni_] = __builtin_amdgcn_mfma_f32_16x16x32_bf16(         \
                WF[ni_], yf_[mi_], acc[mi_][ni_], 0, 0, 0);                  \
} while (0)

__global__ __launch_bounds__(512, 2)
void quad_gemm(const float* __restrict__ x, const s16x8* __restrict__ wpk,
               float* __restrict__ out) {
    __shared__ __align__(16) u16 x_lds[BM * 64];   // bf16 [m][c], 16B-XOR swizzled
    __shared__ u16 runtab[NRUN];
    __shared__ s16x8 ybuf[2][512];                 // [buf][g*128 + m], B-frag order

    const int t   = threadIdx.x;
    const int l   = t & 63;
    const int wv  = t >> 6;                        // wave 0..7
    const int wm  = wv >> 2;                       // 0..1  (M half)
    const int wn4 = (wv & 3) << 2;                 // 0,4,8,12 (N tile base /16)
    const int lan = l & 15, gk = l >> 4;
    const int ycbase = (gk << 7) + wm * 64 + lan;  // Y-frag read base
    const int g2 = t & 3, m2 = t >> 2;             // gen mapping
    const int xmb = m2 << 6, sw = (m2 & 7) << 3;   // x_lds row base + swizzle
    const int ygidx = (g2 << 7) + m2;              // gen write slot

    const int pix0 = blockIdx.x * BM;
    const int b   = pix0 >> 12;
    const int hw0 = pix0 & 4095;
    const float* xb = x + ((size_t)b << 18) + hw0;

    if (t < NRUN) {
        int i, j0; run_decode(t, i, j0);
        runtab[t] = (u16)((i << 8) | j0);
    }

    // stage x tile: 8 threads per channel, 16 f32 each -> bf16 swizzled LDS
    {
        int c = t >> 3, s = t & 7;
        const float* xc = xb + c * 4096 + s * 16;
        #pragma unroll
        for (int p4 = 0; p4 < 4; ++p4) {
            f32x4 v = *(const f32x4*)(xc + p4 * 4);
            #pragma unroll
            for (int e = 0; e < 4; ++e) {
                int m = s * 16 + p4 * 4 + e;
                x_lds[(m << 6) + (c ^ ((m & 7) << 3))] = f2bf_rne(v[e]);
            }
        }
    }

    f32x4 acc[4][4];
    #pragma unroll
    for (int mi = 0; mi < 4; ++mi)
        #pragma unroll
        for (int ni = 0; ni < 4; ++ni)
            acc[mi][ni] = (f32x4){0.f, 0.f, 0.f, 0.f};

    s16x8 W0[4], W1[4];

    __syncthreads();          // runtab + x_lds ready
    GEN(0, 0);
    LOADW(0, W0);
    __syncthreads();          // ybuf[0] ready

    for (int q = 0; q < NQ; q += 2) {
        // phase A: consume q (buf0), prefetch/gen q+1 (buf1)
        LOADW(q + 1, W1);
        GEN(q + 1, 1);
        CONSUME(0, W0);
        __syncthreads();
        // phase B: consume q+1 (buf1), prefetch/gen q+2 (buf0)
        if (q + 2 < NQ) { LOADW(q + 2, W0); GEN(q + 2, 0); }
        CONSUME(1, W1);
        __syncthreads();
    }

    // D layout (A=W, B=Y): o = (lane>>4)*4 + p (+tile), m = lane&15 (+tile)
    float* ob = out + ((size_t)b << 20) + hw0;
    #pragma unroll
    for (int mi = 0; mi < 4; ++mi) {
        int m = wm * 64 + mi * 16 + lan;
        #pragma unroll
        for (int ni = 0; ni < 4; ++ni) {
            int o = (wn4 + ni) * 16 + gk * 4;
            #pragma unroll
            for (int p = 0; p < 4; ++p)
                ob[(size_t)(o + p) * 4096 + m] = acc[mi][ni][p];
        }
    }
}

extern "C" void kernel_launch(void* const* d_in, const int* in_sizes, int n_in,
                              void* d_out, int out_size, void* d_ws, size_t ws_size,
                              hipStream_t stream) {
    const float* x   = (const float*)d_in[0];
    const float* fcw = (const float*)d_in[1];
    float* out = (float*)d_out;
    s16x8* wpk = (s16x8*)d_ws;     // 74*16*64*16B = 1.16 MB

    hipLaunchKernelGGL(pack_w, dim3(NQ * 4), dim3(256), 0, stream, fcw, wpk);
    hipLaunchKernelGGL(quad_gemm, dim3(256), dim3(512), 0, stream,
                       x, (const s16x8*)wpk, out);
}

// Round 2
// 116.468 us; speedup vs baseline: 1.0244x; 1.0244x over previous
//
#include <hip/hip_runtime.h>
#include <hip/hip_bf16.h>

using u16 = unsigned short;
using u32 = unsigned int;

typedef __attribute__((ext_vector_type(8))) short s16x8;
typedef __attribute__((ext_vector_type(4))) float f32x4;
typedef __attribute__((ext_vector_type(4))) u32   u32x4;

#define NQ   74      // K chunks of 32 (2368 padded features)
#define NRUN 296     // 8-runs: 8 linear + 288 quad

__device__ __forceinline__ u16 f2bf_rne(float f) {
    u32 u = __builtin_bit_cast(u32, f);
    u32 r = u + 0x7fffu + ((u >> 16) & 1u);
    return (u16)(r >> 16);
}
__device__ __forceinline__ float bf2f(u16 u) {
    u32 v = ((u32)u) << 16;
    return __builtin_bit_cast(float, v);
}

// run r -> (i, j0). r<8: linear terms (i=64 means "ones"); else quad row i,
// runs start at j0=(i>>3)*8 (leading j<i entries carry zero weights).
__device__ __forceinline__ void run_decode(int r, int& i, int& j0) {
    if (r < 8) { i = 64; j0 = r << 3; return; }
    int rr = r - 8;
    int ii = 0;
    while (true) { int cnt = 8 - (ii >> 3); if (rr < cnt) break; rr -= cnt; ++ii; }
    i = ii;
    j0 = ((ii >> 3) << 3) + (rr << 3);
}

// Repack fc_w [256][2144] f32 -> bf16 MFMA A-fragment order:
// wpk[(q*16+t)*64 + l] holds 8 bf16: n = t*16+(l&15), k-run = q*4+(l>>4), e=0..7
__global__ __launch_bounds__(1024)
void pack_w(const float* __restrict__ fcw, s16x8* __restrict__ wpk) {
    __shared__ u16 runs4[4];
    const int q = blockIdx.x;
    const int t = threadIdx.x;
    if (t < 4) {
        int i, j0; run_decode(q * 4 + t, i, j0);
        runs4[t] = (u16)((i << 8) | j0);
    }
    __syncthreads();
    const int l = t & 63;
    const int g = l >> 4;
    const int n = ((t >> 6) << 4) + (l & 15);
    const u16 ij = runs4[g];
    const int i = ij >> 8, j0 = ij & 255;
    const float* row = fcw + n * 2144;
    short w8[8];
    #pragma unroll
    for (int e = 0; e < 8; ++e) {
        int j = j0 + e;
        float w;
        if (i == 64)    w = row[j];                                            // linear
        else if (j < i) w = 0.f;                                               // pad
        else            w = row[64 + i * 64 - ((i * (i - 1)) >> 1) + (j - i)]; // triu
        w8[e] = (short)f2bf_rne(w);
    }
    s16x8 v = { w8[0], w8[1], w8[2], w8[3], w8[4], w8[5], w8[6], w8[7] };
    wpk[q * 1024 + t] = v;
}

// Stage chunk Q: per-lane B-frag generation straight from x_lds (no ybuf),
// plus the 8 W A-frags for this block's N-half.
#define STAGE(IJ, Y, W, Q) do {                                              \
    const int i_ = (IJ) >> 8, j0_ = (IJ) & 255;                              \
    _Pragma("unroll")                                                        \
    for (int mi_ = 0; mi_ < 2; ++mi_) {                                      \
        u16 fb_ = x_lds[mb[mi_] + ((i_ & 63) ^ sw)];                         \
        s16x8 vj_ = *(const s16x8*)(x_lds + mb[mi_] + (j0_ ^ sw));           \
        float fi_ = (i_ >= 64) ? 1.0f : bf2f(fb_);                           \
        u32 pk_[4];                                                          \
        _Pragma("unroll")                                                    \
        for (int d_ = 0; d_ < 4; ++d_) {                                     \
            float p0_ = fi_ * bf2f((u16)vj_[2 * d_]);                        \
            float p1_ = fi_ * bf2f((u16)vj_[2 * d_ + 1]);                    \
            pk_[d_] = __builtin_amdgcn_perm(__builtin_bit_cast(u32, p1_),    \
                                            __builtin_bit_cast(u32, p0_),    \
                                            0x07060302u);                    \
        }                                                                    \
        u32x4 pv_ = { pk_[0], pk_[1], pk_[2], pk_[3] };                      \
        Y[mi_] = __builtin_bit_cast(s16x8, pv_);                             \
    }                                                                        \
    _Pragma("unroll")                                                        \
    for (int ni_ = 0; ni_ < 8; ++ni_) W[ni_] = wb[(Q) * 1024 + ni_ * 64];    \
} while (0)

#define MFMAQ(Y, W) do {                                                     \
    _Pragma("unroll")                                                        \
    for (int mi_ = 0; mi_ < 2; ++mi_)                                        \
        _Pragma("unroll")                                                    \
        for (int ni_ = 0; ni_ < 8; ++ni_)                                    \
            acc[mi_][ni_] = __builtin_amdgcn_mfma_f32_16x16x32_bf16(         \
                W[ni_], Y[mi_], acc[mi_][ni_], 0, 0, 0);                     \
} while (0)

__global__ __launch_bounds__(256, 2)
void quad_gemm(const float* __restrict__ x, const s16x8* __restrict__ wpk,
               float* __restrict__ out) {
    __shared__ __align__(16) u16 x_lds[128 * 64];   // bf16 [m][c], 16B-XOR swizzled
    __shared__ u16 runtab[NRUN];

    const int t   = threadIdx.x;
    const int l   = t & 63;
    const int wv  = t >> 6;                 // wave 0..3 -> M rows wv*32..wv*32+31
    const int lan = l & 15, gk = l >> 4;

    const int mtile = blockIdx.x >> 1;
    const int nb    = blockIdx.x & 1;       // N half (128 outputs)
    const int pix0  = mtile * 128;
    const int b     = pix0 >> 12;
    const int hw0   = pix0 & 4095;

    for (int r = t; r < NRUN; r += 256) {
        int i, j0; run_decode(r, i, j0);
        runtab[r] = (u16)((i << 8) | j0);
    }

    // stage x tile: 4 threads per channel, 32 f32 each -> bf16 swizzled LDS
    {
        const int c = t >> 2, s = t & 3;
        const float* xc = x + ((size_t)b << 18) + (size_t)c * 4096 + hw0 + s * 32;
        #pragma unroll
        for (int p4 = 0; p4 < 8; ++p4) {
            f32x4 v = *(const f32x4*)(xc + p4 * 4);
            #pragma unroll
            for (int e = 0; e < 4; ++e) {
                int m = s * 32 + p4 * 4 + e;
                x_lds[(m << 6) + (c ^ ((m & 7) << 3))] = f2bf_rne(v[e]);
            }
        }
    }

    f32x4 acc[2][8];
    #pragma unroll
    for (int mi = 0; mi < 2; ++mi)
        #pragma unroll
        for (int ni = 0; ni < 8; ++ni)
            acc[mi][ni] = (f32x4){0.f, 0.f, 0.f, 0.f};

    const int mb[2] = { (wv * 32 + lan) << 6, (wv * 32 + 16 + lan) << 6 };
    const int sw    = (lan & 7) << 3;
    const s16x8* wb = wpk + nb * 512 + l;

    __syncthreads();   // x_lds + runtab ready; NO barriers after this point

    s16x8 Ya[2], Wa[8], Yb[2], Wb[8];
    int ija = runtab[0 * 4 + gk];
    int ijb = runtab[1 * 4 + gk];
    STAGE(ija, Ya, Wa, 0);
    for (int q = 0; q + 2 < NQ; q += 2) {
        ija = runtab[(q + 2) * 4 + gk];
        STAGE(ijb, Yb, Wb, q + 1);
        MFMAQ(Ya, Wa);
        ijb = runtab[(q + 3) * 4 + gk];
        STAGE(ija, Ya, Wa, q + 2);
        MFMAQ(Yb, Wb);
    }
    STAGE(ijb, Yb, Wb, NQ - 1);
    MFMAQ(Ya, Wa);
    MFMAQ(Yb, Wb);

    // D layout (A=W, B=Y): col = lane&15 -> pixel, row = gk*4+p -> out channel
    float* ob = out + ((size_t)b << 20) + hw0;
    #pragma unroll
    for (int mi = 0; mi < 2; ++mi) {
        const int m = wv * 32 + mi * 16 + lan;
        #pragma unroll
        for (int ni = 0; ni < 8; ++ni) {
            const int o = nb * 128 + ni * 16 + gk * 4;
            #pragma unroll
            for (int p = 0; p < 4; ++p)
                ob[(size_t)(o + p) * 4096 + m] = acc[mi][ni][p];
        }
    }
}

extern "C" void kernel_launch(void* const* d_in, const int* in_sizes, int n_in,
                              void* d_out, int out_size, void* d_ws, size_t ws_size,
                              hipStream_t stream) {
    const float* x   = (const float*)d_in[0];
    const float* fcw = (const float*)d_in[1];
    float* out = (float*)d_out;
    s16x8* wpk = (s16x8*)d_ws;     // 74*1024*16B = 1.16 MB

    hipLaunchKernelGGL(pack_w, dim3(NQ), dim3(1024), 0, stream, fcw, wpk);
    hipLaunchKernelGGL(quad_gemm, dim3(512), dim3(256), 0, stream,
                       x, (const s16x8*)wpk, out);
}